// Round 5
// baseline (215.815 us; speedup 1.0000x reference)
//
#include <hip/hip_runtime.h>
#include <math.h>

#define BATCH 1024
#define FIN   256
#define HDIM  512
#define PDIM  128

typedef unsigned short u16;
typedef __attribute__((ext_vector_type(8))) short short8;
typedef __attribute__((ext_vector_type(4))) float fx4;

#define LOG2E 1.4426950408889634f

__device__ __forceinline__ float b2f(u16 b) {
    return __uint_as_float(((unsigned)b) << 16);
}
__device__ __forceinline__ u16 f2b(float f) {
    unsigned u = __float_as_uint(f);
    u += 0x7fffu + ((u >> 16) & 1u);   // RNE
    return (u16)(u >> 16);
}

#if defined(__has_builtin)
#if __has_builtin(__builtin_amdgcn_exp2f)
#define EXP2(x) __builtin_amdgcn_exp2f(x)
#endif
#endif
#ifndef EXP2
#define EXP2(x) __expf(0.69314718055994531f * (x))
#endif

__device__ __forceinline__ float2 pk_fma(float2 a, float2 b, float2 c) {
    float2 d;
    asm("v_pk_fma_f32 %0, %1, %2, %3" : "=v"(d) : "v"(a), "v"(b), "v"(c));
    return d;
}
__device__ __forceinline__ float2 pk_add(float2 a, float2 b) {
    float2 d;
    asm("v_pk_add_f32 %0, %1, %2" : "=v"(d) : "v"(a), "v"(b));
    return d;
}

// ---- GEMM tile config ----
#define BM 64
#define BN 64
#define BK 64
#define LDK 72   // +8 pad: b128 fragment reads are 2-way (free)

// ================= lin0 (inline fp32->bf16 staging) + weight cvt ============
#define NCVT 9
struct CvtArgs {
    const float* src[NCVT];
    u16* dst[NCVT];
    int n4[NCVT];   // float4 count
};

__global__ __launch_bounds__(256) void lin0_cvt_kernel(
    const float* __restrict__ x, const float* __restrict__ wf,
    const float* __restrict__ bi, u16* __restrict__ oh, CvtArgs ca)
{
    const int tid = threadIdx.x;
    if (blockIdx.x >= 128) {
        // ---- weight conversion part (384 blocks) ----
        const int gt = (blockIdx.x - 128) * 256 + tid;
        const int stride = 384 * 256;
        for (int t = 0; t < NCVT; t++) {
            const float4* s4 = (const float4*)ca.src[t];
            ushort4* d4 = (ushort4*)ca.dst[t];
            for (int i = gt; i < ca.n4[t]; i += stride) {
                const float4 f = s4[i];
                ushort4 o;
                o.x = f2b(f.x); o.y = f2b(f.y); o.z = f2b(f.z); o.w = f2b(f.w);
                d4[i] = o;
            }
        }
        return;
    }
    // ---- lin0 GEMM: [1024,512] = x[1024,256] @ wf[512,256]^T + bi ----
    __shared__ __align__(16) u16 As[BM * LDK];
    __shared__ __align__(16) u16 Ws[BM * LDK];
    const int lane = tid & 63, wave = tid >> 6;
    const int wm = wave & 1, wn = wave >> 1;
    const int quad = lane >> 4, l16 = lane & 15;
    const int bn = (blockIdx.x & 7) * BN;
    const int bm = (blockIdx.x >> 3) * BM;
    const int srow = tid >> 3;
    const int scol = (tid & 7) * 8;

    const float* xb = x + (size_t)(bm + srow) * FIN + scol;
    const float* wb = wf + (size_t)(bn + srow) * FIN + scol;

    // prefetch k-tile 0
    float4 fa0 = *(const float4*)xb;
    float4 fa1 = *(const float4*)(xb + 4);
    float4 fa2 = *(const float4*)(xb + (size_t)32 * FIN);
    float4 fa3 = *(const float4*)(xb + (size_t)32 * FIN + 4);
    float4 fw0 = *(const float4*)wb;
    float4 fw1 = *(const float4*)(wb + 4);
    float4 fw2 = *(const float4*)(wb + (size_t)32 * FIN);
    float4 fw3 = *(const float4*)(wb + (size_t)32 * FIN + 4);

    fx4 acc[2][2] = {};
    const int nIter = FIN / BK;    // 4
    for (int it = 0; it < nIter; ++it) {
        // convert current regs -> LDS (single buffer)
        {
            short8 s;
            s[0] = (short)f2b(fa0.x); s[1] = (short)f2b(fa0.y);
            s[2] = (short)f2b(fa0.z); s[3] = (short)f2b(fa0.w);
            s[4] = (short)f2b(fa1.x); s[5] = (short)f2b(fa1.y);
            s[6] = (short)f2b(fa1.z); s[7] = (short)f2b(fa1.w);
            *(short8*)&As[srow * LDK + scol] = s;
            s[0] = (short)f2b(fa2.x); s[1] = (short)f2b(fa2.y);
            s[2] = (short)f2b(fa2.z); s[3] = (short)f2b(fa2.w);
            s[4] = (short)f2b(fa3.x); s[5] = (short)f2b(fa3.y);
            s[6] = (short)f2b(fa3.z); s[7] = (short)f2b(fa3.w);
            *(short8*)&As[(srow + 32) * LDK + scol] = s;
            s[0] = (short)f2b(fw0.x); s[1] = (short)f2b(fw0.y);
            s[2] = (short)f2b(fw0.z); s[3] = (short)f2b(fw0.w);
            s[4] = (short)f2b(fw1.x); s[5] = (short)f2b(fw1.y);
            s[6] = (short)f2b(fw1.z); s[7] = (short)f2b(fw1.w);
            *(short8*)&Ws[srow * LDK + scol] = s;
            s[0] = (short)f2b(fw2.x); s[1] = (short)f2b(fw2.y);
            s[2] = (short)f2b(fw2.z); s[3] = (short)f2b(fw2.w);
            s[4] = (short)f2b(fw3.x); s[5] = (short)f2b(fw3.y);
            s[6] = (short)f2b(fw3.z); s[7] = (short)f2b(fw3.w);
            *(short8*)&Ws[(srow + 32) * LDK + scol] = s;
        }
        __syncthreads();
        // prefetch next k-tile while MFMAs run
        if (it + 1 < nIter) {
            const int kt = (it + 1) * BK;
            fa0 = *(const float4*)(xb + kt);
            fa1 = *(const float4*)(xb + kt + 4);
            fa2 = *(const float4*)(xb + (size_t)32 * FIN + kt);
            fa3 = *(const float4*)(xb + (size_t)32 * FIN + kt + 4);
            fw0 = *(const float4*)(wb + kt);
            fw1 = *(const float4*)(wb + kt + 4);
            fw2 = *(const float4*)(wb + (size_t)32 * FIN + kt);
            fw3 = *(const float4*)(wb + (size_t)32 * FIN + kt + 4);
        }
#pragma unroll
        for (int k0 = 0; k0 < BK; k0 += 32) {
            const short8 a0 = *(const short8*)&As[(wm * 32 +      l16) * LDK + k0 + quad * 8];
            const short8 a1 = *(const short8*)&As[(wm * 32 + 16 + l16) * LDK + k0 + quad * 8];
            const short8 b0 = *(const short8*)&Ws[(wn * 32 +      l16) * LDK + k0 + quad * 8];
            const short8 b1 = *(const short8*)&Ws[(wn * 32 + 16 + l16) * LDK + k0 + quad * 8];
            acc[0][0] = __builtin_amdgcn_mfma_f32_16x16x32_bf16(a0, b0, acc[0][0], 0, 0, 0);
            acc[0][1] = __builtin_amdgcn_mfma_f32_16x16x32_bf16(a0, b1, acc[0][1], 0, 0, 0);
            acc[1][0] = __builtin_amdgcn_mfma_f32_16x16x32_bf16(a1, b0, acc[1][0], 0, 0, 0);
            acc[1][1] = __builtin_amdgcn_mfma_f32_16x16x32_bf16(a1, b1, acc[1][1], 0, 0, 0);
        }
        __syncthreads();
    }
#pragma unroll
    for (int i = 0; i < 2; i++)
#pragma unroll
        for (int j = 0; j < 2; j++) {
            const int n_ = bn + wn * 32 + j * 16 + l16;
            const float bv = bi[n_];
#pragma unroll
            for (int r = 0; r < 4; r++) {
                const int m_ = bm + wm * 32 + i * 16 + quad * 4 + r;
                oh[(size_t)m_ * HDIM + n_] = f2b(acc[i][j][r] + bv);
            }
        }
}

// ================= main bf16 GEMM (double-buffered, fixed loop order) =======
// EPI 0: store bf16(acc+bias); EPI 1: store bf16(res + gelu(acc+bias))
template<int EPI>
__global__ __launch_bounds__(256) void gemm_k(
    const u16* __restrict__ A,
    const u16* __restrict__ W0, const u16* __restrict__ W1, const u16* __restrict__ W2,
    const float* __restrict__ bi0, const float* __restrict__ bi1, const float* __restrict__ bi2,
    u16* __restrict__ o0, u16* __restrict__ o1, u16* __restrict__ o2,
    const u16* __restrict__ res, int Nper, int K, int tilesN)
{
    __shared__ __align__(16) u16 As[2][BM * LDK];
    __shared__ __align__(16) u16 Ws[2][BM * LDK];

    const int tid = threadIdx.x, lane = tid & 63, wave = tid >> 6;
    const int wm = wave & 1, wn = wave >> 1;
    const int quad = lane >> 4, l16 = lane & 15;

    const int which = blockIdx.x / tilesN;
    const int bn = (blockIdx.x % tilesN) * BN;
    const int bm = blockIdx.y * BM;
    const u16* W    = (which == 0) ? W0  : (which == 1) ? W1  : W2;
    const float* bi = (which == 0) ? bi0 : (which == 1) ? bi1 : bi2;
    u16* ob         = (which == 0) ? o0  : (which == 1) ? o1  : o2;

    const int srow = tid >> 3;
    const int scol = (tid & 7) * 8;
    const u16* Ab = A + (size_t)(bm + srow) * K + scol;
    const u16* Wb = W + (size_t)(bn + srow) * K + scol;

    // stage k-tile 0 into buffer 0
    {
        *(short8*)&As[0][srow * LDK + scol]        = *(const short8*)Ab;
        *(short8*)&As[0][(srow + 32) * LDK + scol] = *(const short8*)(Ab + (size_t)32 * K);
        *(short8*)&Ws[0][srow * LDK + scol]        = *(const short8*)Wb;
        *(short8*)&Ws[0][(srow + 32) * LDK + scol] = *(const short8*)(Wb + (size_t)32 * K);
    }

    fx4 acc[2][2] = {};
    const int nIter = K / BK;
    for (int it = 0; it < nIter; ++it) {
        const int cur = it & 1, nxt = cur ^ 1;
        __syncthreads();   // nxt writes from prev iter visible; cur readable
        short8 na0, na1, nw0, nw1;
        const bool has = (it + 1 < nIter);
        if (has) {         // issue prefetch; overlaps the MFMA loop below
            const int kt = (it + 1) * BK;
            na0 = *(const short8*)(Ab + kt);
            na1 = *(const short8*)(Ab + (size_t)32 * K + kt);
            nw0 = *(const short8*)(Wb + kt);
            nw1 = *(const short8*)(Wb + (size_t)32 * K + kt);
        }
#pragma unroll
        for (int k0 = 0; k0 < BK; k0 += 32) {
            const short8 a0 = *(const short8*)&As[cur][(wm * 32 +      l16) * LDK + k0 + quad * 8];
            const short8 a1 = *(const short8*)&As[cur][(wm * 32 + 16 + l16) * LDK + k0 + quad * 8];
            const short8 b0 = *(const short8*)&Ws[cur][(wn * 32 +      l16) * LDK + k0 + quad * 8];
            const short8 b1 = *(const short8*)&Ws[cur][(wn * 32 + 16 + l16) * LDK + k0 + quad * 8];
            acc[0][0] = __builtin_amdgcn_mfma_f32_16x16x32_bf16(a0, b0, acc[0][0], 0, 0, 0);
            acc[0][1] = __builtin_amdgcn_mfma_f32_16x16x32_bf16(a0, b1, acc[0][1], 0, 0, 0);
            acc[1][0] = __builtin_amdgcn_mfma_f32_16x16x32_bf16(a1, b0, acc[1][0], 0, 0, 0);
            acc[1][1] = __builtin_amdgcn_mfma_f32_16x16x32_bf16(a1, b1, acc[1][1], 0, 0, 0);
        }
        if (has) {
            *(short8*)&As[nxt][srow * LDK + scol] = na0;
            *(short8*)&As[nxt][(srow + 32) * LDK + scol] = na1;
            *(short8*)&Ws[nxt][srow * LDK + scol] = nw0;
            *(short8*)&Ws[nxt][(srow + 32) * LDK + scol] = nw1;
        }
    }

#pragma unroll
    for (int i = 0; i < 2; i++)
#pragma unroll
        for (int j = 0; j < 2; j++) {
            const int n_ = bn + wn * 32 + j * 16 + l16;
            const float bv = bi[n_];
#pragma unroll
            for (int r = 0; r < 4; r++) {
                const int m_ = bm + wm * 32 + i * 16 + quad * 4 + r;
                const float vacc = acc[i][j][r] + bv;
                const size_t idx = (size_t)m_ * Nper + n_;
                if (EPI == 0) {
                    ob[idx] = f2b(vacc);
                } else {
                    const float g = 0.5f * vacc * (1.0f + erff(vacc * 0.70710678118654752f));
                    ob[idx] = f2b(b2f(res[idx]) + g);
                }
            }
        }
}

// ========== fc1 GEMM, 32x64 tile (256 blocks), gelu+residual epilogue =======
#define CM 32
__global__ __launch_bounds__(256) void fc1_kernel(
    const u16* __restrict__ A, const u16* __restrict__ W,
    const float* __restrict__ bi, u16* __restrict__ ob,
    const u16* __restrict__ res)
{
    __shared__ __align__(16) u16 As[2][CM * LDK];
    __shared__ __align__(16) u16 Ws[2][BN * LDK];

    const int tid = threadIdx.x, lane = tid & 63, wave = tid >> 6;
    const int wn = wave;                   // 4 waves across N (4x16 = 64)
    const int quad = lane >> 4, l16 = lane & 15;
    const int bn = blockIdx.x * BN;
    const int bm = blockIdx.y * CM;
    const int K = HDIM;

    const int srow = tid >> 3;             // 0..31
    const int scol = (tid & 7) * 8;
    const u16* Ab = A + (size_t)(bm + srow) * K + scol;
    const u16* Wb = W + (size_t)(bn + srow) * K + scol;

    {
        *(short8*)&As[0][srow * LDK + scol]        = *(const short8*)Ab;
        *(short8*)&Ws[0][srow * LDK + scol]        = *(const short8*)Wb;
        *(short8*)&Ws[0][(srow + 32) * LDK + scol] = *(const short8*)(Wb + (size_t)32 * K);
    }

    fx4 acc[2] = {};
    const int nIter = K / BK;   // 8
    for (int it = 0; it < nIter; ++it) {
        const int cur = it & 1, nxt = cur ^ 1;
        __syncthreads();
        short8 na0, nw0, nw1;
        const bool has = (it + 1 < nIter);
        if (has) {
            const int kt = (it + 1) * BK;
            na0 = *(const short8*)(Ab + kt);
            nw0 = *(const short8*)(Wb + kt);
            nw1 = *(const short8*)(Wb + (size_t)32 * K + kt);
        }
#pragma unroll
        for (int k0 = 0; k0 < BK; k0 += 32) {
            const short8 a0 = *(const short8*)&As[cur][(     l16) * LDK + k0 + quad * 8];
            const short8 a1 = *(const short8*)&As[cur][(16 + l16) * LDK + k0 + quad * 8];
            const short8 b  = *(const short8*)&Ws[cur][(wn * 16 + l16) * LDK + k0 + quad * 8];
            acc[0] = __builtin_amdgcn_mfma_f32_16x16x32_bf16(a0, b, acc[0], 0, 0, 0);
            acc[1] = __builtin_amdgcn_mfma_f32_16x16x32_bf16(a1, b, acc[1], 0, 0, 0);
        }
        if (has) {
            *(short8*)&As[nxt][srow * LDK + scol] = na0;
            *(short8*)&Ws[nxt][srow * LDK + scol] = nw0;
            *(short8*)&Ws[nxt][(srow + 32) * LDK + scol] = nw1;
        }
    }

    const int n_ = bn + wn * 16 + l16;
    const float bv = bi[n_];
#pragma unroll
    for (int i = 0; i < 2; i++)
#pragma unroll
        for (int r = 0; r < 4; r++) {
            const int m_ = bm + i * 16 + quad * 4 + r;
            const float vacc = acc[i][r] + bv;
            const size_t idx = (size_t)m_ * HDIM + n_;
            const float g = 0.5f * vacc * (1.0f + erff(vacc * 0.70710678118654752f));
            ob[idx] = f2b(b2f(res[idx]) + g);
        }
}

// ================= attention (unchanged from R4 — control) ==================
__global__ __launch_bounds__(256) void attn_kernel(
    const u16* __restrict__ h, const u16* __restrict__ q,
    const u16* __restrict__ k, const u16* __restrict__ v,
    u16* __restrict__ hout)
{
    __shared__ __align__(16) float ks[HDIM];
    __shared__ __align__(16) float vs[HDIM];
    __shared__ float red[8];

    const int b = blockIdx.x;
    const int tid = threadIdx.x;
    const int lane = tid & 63, wave = tid >> 6;
    const int i0 = tid, i1 = tid + 256;
    const size_t base = (size_t)b * HDIM;

    const float k0 = b2f(k[base + i0]);
    const float k1 = b2f(k[base + i1]);
    ks[i0] = k0; ks[i1] = k1;
    vs[i0] = b2f(v[base + i0]);
    vs[i1] = b2f(v[base + i1]);

    float lmax = fmaxf(k0, k1), lmin = fminf(k0, k1);
#pragma unroll
    for (int off = 32; off; off >>= 1) {
        lmax = fmaxf(lmax, __shfl_xor(lmax, off));
        lmin = fminf(lmin, __shfl_xor(lmin, off));
    }
    if (lane == 0) { red[wave] = lmax; red[4 + wave] = lmin; }
    __syncthreads();
    const float kmax = fmaxf(fmaxf(red[0], red[1]), fmaxf(red[2], red[3]));
    const float kmin = fminf(fminf(red[4], red[5]), fminf(red[6], red[7]));

    float s0 = b2f(q[base + i0]);
    float s1 = b2f(q[base + i1]);
    const float mn0 = -((s0 > 0.f) ? s0 * kmax : s0 * kmin) * LOG2E;
    const float mn1 = -((s1 > 0.f) ? s1 * kmax : s1 * kmin) * LOG2E;
    s0 *= LOG2E; s1 *= LOG2E;

    const float2 s0_2  = make_float2(s0, s0),  s1_2  = make_float2(s1, s1);
    const float2 mn0_2 = make_float2(mn0, mn0), mn1_2 = make_float2(mn1, mn1);
    float2 D0 = make_float2(0.f, 0.f), N0 = D0, D1 = D0, N1 = D0;

    const float4* k4 = (const float4*)ks;
    const float4* v4 = (const float4*)vs;
#pragma unroll 4
    for (int j = 0; j < HDIM / 4; j++) {
        const float4 kk = k4[j];
        const float4 vv = v4[j];
        {
            float2 a0 = pk_fma(s0_2, make_float2(kk.x, kk.y), mn0_2);
            float2 e0; e0.x = EXP2(a0.x); e0.y = EXP2(a0.y);
            D0 = pk_add(D0, e0);
            N0 = pk_fma(e0, make_float2(vv.x, vv.y), N0);
            float2 a1 = pk_fma(s0_2, make_float2(kk.z, kk.w), mn0_2);
            float2 e1; e1.x = EXP2(a1.x); e1.y = EXP2(a1.y);
            D0 = pk_add(D0, e1);
            N0 = pk_fma(e1, make_float2(vv.z, vv.w), N0);
        }
        {
            float2 a0 = pk_fma(s1_2, make_float2(kk.x, kk.y), mn1_2);
            float2 e0; e0.x = EXP2(a0.x); e0.y = EXP2(a0.y);
            D1 = pk_add(D1, e0);
            N1 = pk_fma(e0, make_float2(vv.x, vv.y), N1);
            float2 a1 = pk_fma(s1_2, make_float2(kk.z, kk.w), mn1_2);
            float2 e1; e1.x = EXP2(a1.x); e1.y = EXP2(a1.y);
            D1 = pk_add(D1, e1);
            N1 = pk_fma(e1, make_float2(vv.z, vv.w), N1);
        }
    }
    hout[base + i0] = f2b(b2f(h[base + i0]) + (N0.x + N0.y) / (D0.x + D0.y));
    hout[base + i1] = f2b(b2f(h[base + i1]) + (N1.x + N1.y) / (D1.x + D1.y));
}

// ================= fea GEMM (BN = full 128) + fused regression head =========
#define FM 64
#define FN 128
__global__ __launch_bounds__(256) void fea_head_kernel(
    const u16* __restrict__ A, const u16* __restrict__ Wf,
    const float* __restrict__ fb, const float* __restrict__ rw,
    const float* __restrict__ rb, float* __restrict__ fea, float* __restrict__ out)
{
    __shared__ __align__(16) u16 As[2][FM * LDK];
    __shared__ __align__(16) u16 Ws[2][FN * LDK];
    __shared__ float red[2][FM];

    const int tid = threadIdx.x, lane = tid & 63, wave = tid >> 6;
    const int wm = wave & 1, wn = wave >> 1;
    const int quad = lane >> 4, l16 = lane & 15;
    const int bm = blockIdx.x * FM;
    const int srow = tid >> 3;
    const int scol = (tid & 7) * 8;
    const int K = HDIM;

    const u16* Ab = A + (size_t)(bm + srow) * K + scol;
    const u16* Wb = Wf + (size_t)srow * K + scol;

    {
        *(short8*)&As[0][srow * LDK + scol]        = *(const short8*)Ab;
        *(short8*)&As[0][(srow + 32) * LDK + scol] = *(const short8*)(Ab + (size_t)32 * K);
#pragma unroll
        for (int c = 0; c < 4; c++)
            *(short8*)&Ws[0][(srow + 32 * c) * LDK + scol] =
                *(const short8*)(Wb + (size_t)(32 * c) * K);
    }

    fx4 acc[2][4] = {};
    const int nIter = K / BK;
    for (int it = 0; it < nIter; ++it) {
        const int cur = it & 1, nxt = cur ^ 1;
        __syncthreads();
        short8 na0, na1, nw[4];
        const bool has = (it + 1 < nIter);
        if (has) {
            const int kt = (it + 1) * BK;
            na0 = *(const short8*)(Ab + kt);
            na1 = *(const short8*)(Ab + (size_t)32 * K + kt);
#pragma unroll
            for (int c = 0; c < 4; c++)
                nw[c] = *(const short8*)(Wb + (size_t)(32 * c) * K + kt);
        }
#pragma unroll
        for (int k0 = 0; k0 < BK; k0 += 32) {
            const short8 a0 = *(const short8*)&As[cur][(wm * 32 +      l16) * LDK + k0 + quad * 8];
            const short8 a1 = *(const short8*)&As[cur][(wm * 32 + 16 + l16) * LDK + k0 + quad * 8];
#pragma unroll
            for (int j = 0; j < 4; j++) {
                const short8 bj = *(const short8*)&Ws[cur][(wn * 64 + j * 16 + l16) * LDK + k0 + quad * 8];
                acc[0][j] = __builtin_amdgcn_mfma_f32_16x16x32_bf16(a0, bj, acc[0][j], 0, 0, 0);
                acc[1][j] = __builtin_amdgcn_mfma_f32_16x16x32_bf16(a1, bj, acc[1][j], 0, 0, 0);
            }
        }
        if (has) {
            *(short8*)&As[nxt][srow * LDK + scol] = na0;
            *(short8*)&As[nxt][(srow + 32) * LDK + scol] = na1;
#pragma unroll
            for (int c = 0; c < 4; c++)
                *(short8*)&Ws[nxt][(srow + 32 * c) * LDK + scol] = nw[c];
        }
    }

    // epilogue: store fea fp32 + fused head partial
#pragma unroll
    for (int i = 0; i < 2; i++) {
#pragma unroll
        for (int r = 0; r < 4; r++) {
            const int m_ = bm + wm * 32 + i * 16 + quad * 4 + r;
            float hp = 0.f;
#pragma unroll
            for (int j = 0; j < 4; j++) {
                const int n_ = wn * 64 + j * 16 + l16;
                const float vacc = acc[i][j][r] + fb[n_];
                fea[(size_t)m_ * PDIM + n_] = vacc;
                hp = fmaf(vacc, rw[n_], hp);
            }
#pragma unroll
            for (int off = 1; off < 16; off <<= 1) hp += __shfl_xor(hp, off);
            if (l16 == 0) red[wn][wm * 32 + i * 16 + quad * 4 + r] = hp;
        }
    }
    __syncthreads();
    if (tid < FM) out[bm + tid] = red[0][tid] + red[1][tid] + rb[0];
}

extern "C" void kernel_launch(void* const* d_in, const int* in_sizes, int n_in,
                              void* d_out, int out_size, void* d_ws, size_t ws_size,
                              hipStream_t stream) {
    const float* x      = (const float*)d_in[0];
    const float* lin0_w = (const float*)d_in[1];
    const float* lin0_b = (const float*)d_in[2];
    const float* b1_qw  = (const float*)d_in[3];
    const float* b1_qb  = (const float*)d_in[4];
    const float* b1_kw  = (const float*)d_in[5];
    const float* b1_kb  = (const float*)d_in[6];
    const float* b1_vw  = (const float*)d_in[7];
    const float* b1_vb  = (const float*)d_in[8];
    const float* b1_f1w = (const float*)d_in[9];
    const float* b1_f1b = (const float*)d_in[10];
    const float* b2_qw  = (const float*)d_in[11];
    const float* b2_qb  = (const float*)d_in[12];
    const float* b2_kw  = (const float*)d_in[13];
    const float* b2_kb  = (const float*)d_in[14];
    const float* b2_vw  = (const float*)d_in[15];
    const float* b2_vb  = (const float*)d_in[16];
    const float* b2_f1w = (const float*)d_in[17];
    const float* b2_f1b = (const float*)d_in[18];
    const float* fea_w  = (const float*)d_in[19];
    const float* fea_b  = (const float*)d_in[20];
    const float* reg_w  = (const float*)d_in[21];
    const float* reg_b  = (const float*)d_in[22];

    float* out = (float*)d_out;
    float* fea = out + BATCH;

    u16* wsb = (u16*)d_ws;
    const size_t SZ_HH = (size_t)HDIM * HDIM;   // 262144
    const size_t SZ_FE = (size_t)PDIM * HDIM;   // 65536
    const size_t SZ_AC = (size_t)BATCH * HDIM;  // 524288

    u16* w1q = wsb;
    u16* w1k = w1q + SZ_HH;
    u16* w1v = w1k + SZ_HH;
    u16* w1f = w1v + SZ_HH;
    u16* w2q = w1f + SZ_HH;
    u16* w2k = w2q + SZ_HH;
    u16* w2v = w2k + SZ_HH;
    u16* w2f = w2v + SZ_HH;
    u16* wfe = w2f + SZ_HH;
    u16* hA  = wfe + SZ_FE;
    u16* hB  = hA + SZ_AC;
    u16* qb  = hB + SZ_AC;
    u16* kb  = qb + SZ_AC;
    u16* vb  = kb + SZ_AC;

    CvtArgs ca;
    const float* srcs[NCVT] = {b1_qw, b1_kw, b1_vw, b1_f1w, b2_qw, b2_kw, b2_vw, b2_f1w, fea_w};
    u16* dsts[NCVT] = {w1q, w1k, w1v, w1f, w2q, w2k, w2v, w2f, wfe};
    const int n4s[NCVT] = {65536, 65536, 65536, 65536, 65536, 65536, 65536, 65536, 16384};
    for (int i = 0; i < NCVT; i++) { ca.src[i] = srcs[i]; ca.dst[i] = dsts[i]; ca.n4[i] = n4s[i]; }

    const dim3 blk(256);
    const dim3 g_qkv(3 * HDIM / BN, BATCH / BM);   // (24,16) = 384 blocks
    const dim3 g_fc1(HDIM / BN, BATCH / CM);       // (8,32)  = 256 blocks

    // lin0 + weight conversion (one dispatch)
    lin0_cvt_kernel<<<512, blk, 0, stream>>>(x, lin0_w, lin0_b, hA, ca);

    // block 1
    gemm_k<0><<<g_qkv, blk, 0, stream>>>(hA, w1q, w1k, w1v, b1_qb, b1_kb, b1_vb,
                                         qb, kb, vb, nullptr, HDIM, HDIM, HDIM / BN);
    attn_kernel<<<BATCH, blk, 0, stream>>>(hA, qb, kb, vb, hB);
    fc1_kernel<<<g_fc1, blk, 0, stream>>>(hB, w1f, b1_f1b, hA, hB);
    // block 2
    gemm_k<0><<<g_qkv, blk, 0, stream>>>(hA, w2q, w2k, w2v, b2_qb, b2_kb, b2_vb,
                                         qb, kb, vb, nullptr, HDIM, HDIM, HDIM / BN);
    attn_kernel<<<BATCH, blk, 0, stream>>>(hA, qb, kb, vb, hB);
    fc1_kernel<<<g_fc1, blk, 0, stream>>>(hB, w2f, b2_f1b, hA, hB);

    // fea + head (one dispatch)
    fea_head_kernel<<<BATCH / FM, blk, 0, stream>>>(hA, wfe, fea_b, reg_w, reg_b, fea, out);
}